// Round 6
// baseline (205.549 us; speedup 1.0000x reference)
//
#include <hip/hip_runtime.h>

// RFCM loss, fused single pass + finalize. B=2, K=4, D=H=W=128. Scalar out.
//
// mean(J1) = (1/(B*N)) * sum_{b,k} [ A_bk - Sim_bk^2 / Sm_bk ]
//   Sm=sum mem, Sim=sum mem*img, A=sum mem*img^2, mem=y_pred^2
// mean(J2) = (1/(B*N)) * sum_n [ Sm*Sbk - Sm^2 - sum_k m*bk + sum_k m^2 ]
//   bk = box27(mem_k) incl center, zero pad.
//
// R6: occupancy attack via VGPR. Session evidence: occupancy only moved with
// VGPR (R4: 64 regs -> 41.9% occ; R3/R5: 136-168 regs -> ~8.5%). R4 lost to
// spills (326 MB scratch). Here: no pipeline arrays (-48 live regs),
// launch_bounds(256,4) pins VGPR<=128 (natural est ~110 -> no spill),
// 1024 blocks x 4 waves = 16 waves/CU demand = VGPR cap. Keep shfl w-halo
// (13 VMEM/step) + XCD swizzle.

#define BB 2
#define KK 4
#define DD 128
#define HH 128
#define WW 128
#define PLANE (HH * WW)
#define SD 4
#define NBD (DD / SD)   // 32
#define HR 8            // rows per block
#define NBH (HH / HR)   // 16
#define NT 256          // 32 w-lanes x 8 rows

__global__ __launch_bounds__(NT, 4) void rfcm_main(
    const float* __restrict__ yp, const float* __restrict__ img,
    double* __restrict__ ws)
{
    const int tid = threadIdx.x;
    const int wl  = tid & 31;       // w-lane: owns cols c0..c0+3
    const int hr  = tid >> 5;       // 0..7: own row
    const int c0  = wl << 2;

    // XCD swizzle: 16 ht-tiles of one (b,dsb) slab share one XCD's L2.
    const int bid = blockIdx.x;
    const int xcd = bid & 7;
    const int s   = bid >> 3;          // 0..127
    const int gi  = s >> 4;            // 0..7
    const int ht  = s & 15;
    const int grp = (gi << 3) | xcd;   // 0..63
    const int b   = grp >> 5;
    const int dsb = grp & 31;

    const int h   = ht * HR + hr;
    const int d0  = dsb * SD;

    const bool okL = (wl > 0), okR = (wl < 31);
    const float msc = (h > 0)      ? 1.f : 0.f;
    const float psc = (h < HH - 1) ? 1.f : 0.f;
    const int hm = (h > 0)      ? h - 1 : h;
    const int hp = (h < HH - 1) ? h + 1 : h;

    const float* base = yp + (size_t)b * KK * DD * PLANE;
    const int offM = hm * WW + c0;
    const int off0 = h  * WW + c0;
    const int offP = hp * WW + c0;

    // load 3 rows of plane t for cluster k -> hw9 box sum (s9) + center sq (mm)
    auto mk_s9 = [&](int t, int k, float4& s9, float4& mm) {
        if ((unsigned)t < (unsigned)DD) {
            const float* pt = base + ((size_t)(k * DD + t)) * PLANE;
            const float4 a4 = *(const float4*)(pt + offM);
            const float4 b4 = *(const float4*)(pt + off0);
            const float4 c4 = *(const float4*)(pt + offP);

            float4 sb = make_float4(b4.x*b4.x, b4.y*b4.y, b4.z*b4.z, b4.w*b4.w);
            mm = sb;
            float4 v;   // vertical 3-sum of squares, own 4 cols
            v.x = fmaf(a4.x*a4.x, msc, fmaf(c4.x*c4.x, psc, sb.x));
            v.y = fmaf(a4.y*a4.y, msc, fmaf(c4.y*c4.y, psc, sb.y));
            v.z = fmaf(a4.z*a4.z, msc, fmaf(c4.z*c4.z, psc, sb.z));
            v.w = fmaf(a4.w*a4.w, msc, fmaf(c4.w*c4.w, psc, sb.w));
            // w-halo via cross-lane (row wrap masked to 0 at w boundary)
            const float vL = okL ? __shfl_up(v.w, 1)   : 0.f;
            const float vR = okR ? __shfl_down(v.x, 1) : 0.f;
            s9.x = vL  + v.x + v.y;
            s9.y = v.x + v.y + v.z;
            s9.z = v.y + v.z + v.w;
            s9.w = v.z + v.w + vR;
        } else {
            s9 = make_float4(0.f, 0.f, 0.f, 0.f);
            mm = make_float4(0.f, 0.f, 0.f, 0.f);
        }
    };

    float4 s9p[KK], s9c[KK], mc[KK], dumm;
    #pragma unroll
    for (int k = 0; k < KK; k++) mk_s9(d0 - 1, k, s9p[k], dumm);
    #pragma unroll
    for (int k = 0; k < KK; k++) mk_s9(d0, k, s9c[k], mc[k]);

    float smf[KK] = {0,0,0,0}, sif[KK] = {0,0,0,0}, saf[KK] = {0,0,0,0};
    float j2f = 0.f;

    const float* imgb = img + (size_t)b * DD * PLANE + off0;

    #pragma unroll
    for (int i = 0; i < SD; i++) {
        const int d = d0 + i;

        const float4 iv = *(const float4*)(imgb + (size_t)d * PLANE);
        const float4 iv2 = make_float4(iv.x*iv.x, iv.y*iv.y, iv.z*iv.z, iv.w*iv.w);

        float4 summ  = make_float4(0.f, 0.f, 0.f, 0.f);
        float4 sumbk = make_float4(0.f, 0.f, 0.f, 0.f);
        float4 cross = make_float4(0.f, 0.f, 0.f, 0.f);

        #pragma unroll
        for (int k = 0; k < KK; k++) {
            float4 s9n, mn;
            mk_s9(d + 1, k, s9n, mn);

            const float4 m = mc[k];
            float4 bk;
            bk.x = s9p[k].x + s9c[k].x + s9n.x;
            bk.y = s9p[k].y + s9c[k].y + s9n.y;
            bk.z = s9p[k].z + s9c[k].z + s9n.z;
            bk.w = s9p[k].w + s9c[k].w + s9n.w;

            summ.x += m.x; summ.y += m.y; summ.z += m.z; summ.w += m.w;
            sumbk.x += bk.x; sumbk.y += bk.y; sumbk.z += bk.z; sumbk.w += bk.w;
            cross.x = fmaf(m.x, bk.x - m.x, cross.x);
            cross.y = fmaf(m.y, bk.y - m.y, cross.y);
            cross.z = fmaf(m.z, bk.z - m.z, cross.z);
            cross.w = fmaf(m.w, bk.w - m.w, cross.w);

            smf[k] += (m.x + m.y) + (m.z + m.w);
            sif[k] = fmaf(m.x, iv.x,  fmaf(m.y, iv.y,  fmaf(m.z, iv.z,  fmaf(m.w, iv.w,  sif[k]))));
            saf[k] = fmaf(m.x, iv2.x, fmaf(m.y, iv2.y, fmaf(m.z, iv2.z, fmaf(m.w, iv2.w, saf[k]))));

            s9p[k] = s9c[k]; s9c[k] = s9n; mc[k] = mn;
        }

        j2f += (summ.x * (sumbk.x - summ.x) - cross.x)
             + (summ.y * (sumbk.y - summ.y) - cross.y)
             + (summ.z * (sumbk.z - summ.z) - cross.z)
             + (summ.w * (sumbk.w - summ.w) - cross.w);
    }

    // ---- block reduction of 13 scalars ----
    double q[13];
    #pragma unroll
    for (int k = 0; k < KK; k++) {
        q[k] = (double)smf[k]; q[4 + k] = (double)sif[k]; q[8 + k] = (double)saf[k];
    }
    q[12] = (double)j2f;

    #pragma unroll
    for (int qq = 0; qq < 13; qq++) {
        double v = q[qq];
        #pragma unroll
        for (int off = 32; off > 0; off >>= 1) v += __shfl_down(v, off, 64);
        q[qq] = v;
    }

    __shared__ double red[4 * 13];
    const int lane = tid & 63, wid = tid >> 6;
    if (lane == 0) {
        #pragma unroll
        for (int qq = 0; qq < 13; qq++) red[wid * 13 + qq] = q[qq];
    }
    __syncthreads();
    if (tid < 13) {
        const double sfin = red[tid] + red[13 + tid] + red[26 + tid] + red[39 + tid];
        int idx;
        if      (tid < 4)  idx = b * KK + tid;              // Sm
        else if (tid < 8)  idx = 8  + b * KK + (tid - 4);   // Sim
        else if (tid < 12) idx = 16 + b * KK + (tid - 8);   // A
        else               idx = 24;                        // J2
        unsafeAtomicAdd(&ws[idx], sfin);
    }
}

__global__ void rfcm_fin(const double* __restrict__ ws, float* __restrict__ out)
{
    if (threadIdx.x == 0 && blockIdx.x == 0) {
        double j1 = 0;
        #pragma unroll
        for (int i = 0; i < BB * KK; i++)
            j1 += ws[16 + i] - ws[8 + i] * ws[8 + i] / ws[i];
        const double invBN = 1.0 / ((double)BB * (double)DD * (double)HH * (double)WW);
        out[0] = (float)(j1 * invBN + 0.0008 * ws[24] * invBN);
    }
}

extern "C" void kernel_launch(void* const* d_in, const int* in_sizes, int n_in,
                              void* d_out, int out_size, void* d_ws, size_t ws_size,
                              hipStream_t stream) {
    const float* yp  = (const float*)d_in[0];   // y_pred [2,4,128,128,128]
    const float* img = (const float*)d_in[1];   // image  [2,1,128,128,128]
    float* out = (float*)d_out;
    double* ws = (double*)d_ws;

    hipMemsetAsync(d_ws, 0, 25 * sizeof(double), stream);

    dim3 grid(BB * NBD * NBH);   // 1024 blocks
    rfcm_main<<<grid, NT, 0, stream>>>(yp, img, ws);
    rfcm_fin<<<1, 64, 0, stream>>>(ws, out);
}

// Round 7
// 132.977 us; speedup vs baseline: 1.5457x; 1.5457x over previous
//
#include <hip/hip_runtime.h>

// RFCM loss, fused single pass + finalize. B=2, K=4, D=H=W=128. Scalar out.
//
// mean(J1) = (1/(B*N)) * sum_{b,k} [ A_bk - Sim_bk^2 / Sm_bk ]
//   Sm=sum mem, Sim=sum mem*img, A=sum mem*img^2, mem=y_pred^2
// mean(J2) = (1/(B*N)) * sum_n [ Sm*Sbk - Sm^2 - sum_k m*bk + sum_k m^2 ]
//   bk = box27(mem_k) incl center, zero pad.
//
// R7: miss-concurrency attack. Session evidence: dur == hbm_bytes / ~0.9 TB/s
// in every good round -> serialized L3-miss latency (register-pressured
// load->wait->consume). Fix: global_load_lds DMA staging (no dest VGPRs,
// fire-and-forget), double-buffered LDS plane ring, 1 barrier/iter.
// NEVER use __launch_bounds__ min-waves arg here: twice (R4,R6) it forced
// VGPR=64 -> 240-330 MB scratch spills.

#define BB 2
#define KK 4
#define DD 128
#define HH 128
#define WW 128
#define PLANE (HH * WW)
#define SD 16
#define NBD (DD / SD)   // 8
#define HR 4            // rows owned per block
#define NBH (HH / HR)   // 32
#define NT 128          // 32 w-lanes x 4 rows
#define LROW 128
#define LPLANE (6 * LROW)      // 6 rows per (plane,k)
#define LBUF (KK * LPLANE)     // 3072 floats = 12 KB per buffer

typedef const void __attribute__((address_space(1))) gvoid_t;
typedef void __attribute__((address_space(3))) svoid_t;
#define GLD(gp, lp) __builtin_amdgcn_global_load_lds((gvoid_t*)(gp), (svoid_t*)(lp), 16, 0, 0)

__global__ __launch_bounds__(NT) void rfcm_main(
    const float* __restrict__ yp, const float* __restrict__ img,
    double* __restrict__ ws)
{
    __shared__ __align__(16) float sbuf[2 * LBUF];   // 24 KB double buffer

    const int tid = threadIdx.x;
    const int wl  = tid & 31;       // w-lane: owns cols c0..c0+3
    const int hr  = tid >> 5;       // 0..3: own row
    const int c0  = wl << 2;

    // XCD swizzle: 512 blocks; xcd = bid&7; each XCD hosts 2 (b,dsb) slabs
    // whose 32 h-tiles all live there -> h-halo re-reads hit that XCD's L2.
    const int bid  = blockIdx.x;
    const int xcd  = bid & 7;
    const int idx  = bid >> 3;       // 0..63
    const int sl   = idx >> 5;       // 0..1
    const int ht   = idx & 31;
    const int slab = sl * 8 + xcd;   // 0..15
    const int b    = slab >> 3;
    const int dsb  = slab & 7;

    const int h0 = ht * HR;
    const int d0 = dsb * SD;
    const int h  = h0 + hr;

    // ---- DMA staging: plane t (6 rows x 128 cols x 4 clusters) -> buf sel ----
    // Wave wv handles clusters 2wv, 2wv+1; 3 two-row 64-lane DMAs per cluster.
    // LDS dest = wave-uniform base + lane*16 (HW pattern). Global side is
    // per-lane addresses with h-clamp (clamped rows masked by msc/psc later).
    const int wv = tid >> 6;            // 0..1
    const int L  = tid & 63;
    const int rr = L >> 5;              // row within 2-row chunk
    const int cl = (L & 31) << 2;       // col (floats)

    auto dma_plane = [&](int t, int sel) {
        if ((unsigned)t >= (unsigned)DD) return;
        #pragma unroll
        for (int k2 = 0; k2 < 2; k2++) {
            const int k = (wv << 1) | k2;
            const float* pb = yp + (size_t)((b * KK + k) * DD + t) * PLANE;
            #pragma unroll
            for (int c = 0; c < 3; c++) {
                const int r = (c << 1) + rr;          // lds row 0..5
                int g = h0 - 1 + r;                   // global row, clamped
                g = g < 0 ? 0 : (g > HH - 1 ? HH - 1 : g);
                const float* gp = pb + g * WW + cl;
                float* lp = &sbuf[sel * LBUF + k * LPLANE + (c << 1) * LROW];
                GLD(gp, lp);
            }
        }
    };

    const bool okL = (wl > 0), okR = (wl < 31);
    const float msc = (h > 0)      ? 1.f : 0.f;
    const float psc = (h < HH - 1) ? 1.f : 0.f;

    // extract hw9 3x3 box sum + center squares for cluster k from buf sel
    auto extract = [&](int sel, int k, float4& s9, float4& mm) {
        const float* p3 = &sbuf[sel * LBUF + k * LPLANE + hr * LROW + c0];
        const float4 a4 = *(const float4*)(p3);              // row h-1
        const float4 b4 = *(const float4*)(p3 + LROW);       // row h
        const float4 c4 = *(const float4*)(p3 + 2 * LROW);   // row h+1
        const float4 sb = make_float4(b4.x*b4.x, b4.y*b4.y, b4.z*b4.z, b4.w*b4.w);
        mm = sb;
        float4 v;
        v.x = fmaf(a4.x*a4.x, msc, fmaf(c4.x*c4.x, psc, sb.x));
        v.y = fmaf(a4.y*a4.y, msc, fmaf(c4.y*c4.y, psc, sb.y));
        v.z = fmaf(a4.z*a4.z, msc, fmaf(c4.z*c4.z, psc, sb.z));
        v.w = fmaf(a4.w*a4.w, msc, fmaf(c4.w*c4.w, psc, sb.w));
        const float vL = okL ? __shfl_up(v.w, 1)   : 0.f;
        const float vR = okR ? __shfl_down(v.x, 1) : 0.f;
        s9.x = vL  + v.x + v.y;
        s9.y = v.x + v.y + v.z;
        s9.z = v.y + v.z + v.w;
        s9.w = v.z + v.w + vR;
    };

    // ---- prolog ----
    dma_plane(d0 - 1, 0);            // skipped internally when d0==0
    dma_plane(d0,     1);
    __syncthreads();                 // drains both DMAs

    float4 s9p[KK], s9c[KK], mc[KK], dum;
    const bool vprev = (d0 > 0);
    #pragma unroll
    for (int k = 0; k < KK; k++) {
        if (vprev) extract(0, k, s9p[k], dum);
        else       s9p[k] = make_float4(0.f, 0.f, 0.f, 0.f);
        extract(1, k, s9c[k], mc[k]);
    }
    __syncthreads();                 // buf0 reads done -> safe to re-DMA
    dma_plane(d0 + 1, 0);            // d0+1 <= 113, always valid

    float smf[KK] = {0,0,0,0}, sif[KK] = {0,0,0,0}, saf[KK] = {0,0,0,0};
    float j2f = 0.f;

    const float* imgb = img + (size_t)b * DD * PLANE + h * WW + c0;

    #pragma unroll 2
    for (int i = 0; i < SD; i++) {
        const int d = d0 + i;
        __syncthreads();                           // drains DMA(d+1 -> buf[i&1])
        if (i < SD - 1) dma_plane(d + 2, (i + 1) & 1);  // target last read iter i-1

        const float4 iv = *(const float4*)(imgb + (size_t)d * PLANE);
        const bool vn = (d + 1 < DD);

        float4 summ  = make_float4(0.f, 0.f, 0.f, 0.f);
        float4 sumbk = make_float4(0.f, 0.f, 0.f, 0.f);
        float4 cross = make_float4(0.f, 0.f, 0.f, 0.f);
        const float4 iv2 = make_float4(iv.x*iv.x, iv.y*iv.y, iv.z*iv.z, iv.w*iv.w);

        #pragma unroll
        for (int k = 0; k < KK; k++) {
            float4 s9n, mn;
            if (vn) extract(i & 1, k, s9n, mn);
            else { s9n = make_float4(0.f,0.f,0.f,0.f); mn = s9n; }

            const float4 m = mc[k];
            float4 bk;
            bk.x = s9p[k].x + s9c[k].x + s9n.x;
            bk.y = s9p[k].y + s9c[k].y + s9n.y;
            bk.z = s9p[k].z + s9c[k].z + s9n.z;
            bk.w = s9p[k].w + s9c[k].w + s9n.w;

            summ.x += m.x; summ.y += m.y; summ.z += m.z; summ.w += m.w;
            sumbk.x += bk.x; sumbk.y += bk.y; sumbk.z += bk.z; sumbk.w += bk.w;
            cross.x = fmaf(m.x, bk.x - m.x, cross.x);
            cross.y = fmaf(m.y, bk.y - m.y, cross.y);
            cross.z = fmaf(m.z, bk.z - m.z, cross.z);
            cross.w = fmaf(m.w, bk.w - m.w, cross.w);

            smf[k] += (m.x + m.y) + (m.z + m.w);
            sif[k] = fmaf(m.x, iv.x,  fmaf(m.y, iv.y,  fmaf(m.z, iv.z,  fmaf(m.w, iv.w,  sif[k]))));
            saf[k] = fmaf(m.x, iv2.x, fmaf(m.y, iv2.y, fmaf(m.z, iv2.z, fmaf(m.w, iv2.w, saf[k]))));

            s9p[k] = s9c[k]; s9c[k] = s9n; mc[k] = mn;
        }

        j2f += (summ.x * (sumbk.x - summ.x) - cross.x)
             + (summ.y * (sumbk.y - summ.y) - cross.y)
             + (summ.z * (sumbk.z - summ.z) - cross.z)
             + (summ.w * (sumbk.w - summ.w) - cross.w);
    }

    // ---- block reduction of 13 scalars ----
    double q[13];
    #pragma unroll
    for (int k = 0; k < KK; k++) {
        q[k] = (double)smf[k]; q[4 + k] = (double)sif[k]; q[8 + k] = (double)saf[k];
    }
    q[12] = (double)j2f;

    #pragma unroll
    for (int qq = 0; qq < 13; qq++) {
        double v = q[qq];
        #pragma unroll
        for (int off = 32; off > 0; off >>= 1) v += __shfl_down(v, off, 64);
        q[qq] = v;
    }

    __syncthreads();                 // sbuf reads all done; reuse as scratch
    double* red = (double*)sbuf;
    const int lane = tid & 63, wid = tid >> 6;
    if (lane == 0) {
        #pragma unroll
        for (int qq = 0; qq < 13; qq++) red[wid * 13 + qq] = q[qq];
    }
    __syncthreads();
    if (tid < 13) {
        const double sfin = red[tid] + red[13 + tid];
        int idxo;
        if      (tid < 4)  idxo = b * KK + tid;              // Sm
        else if (tid < 8)  idxo = 8  + b * KK + (tid - 4);   // Sim
        else if (tid < 12) idxo = 16 + b * KK + (tid - 8);   // A
        else               idxo = 24;                        // J2
        unsafeAtomicAdd(&ws[idxo], sfin);
    }
}

__global__ void rfcm_fin(const double* __restrict__ ws, float* __restrict__ out)
{
    if (threadIdx.x == 0 && blockIdx.x == 0) {
        double j1 = 0;
        #pragma unroll
        for (int i = 0; i < BB * KK; i++)
            j1 += ws[16 + i] - ws[8 + i] * ws[8 + i] / ws[i];
        const double invBN = 1.0 / ((double)BB * (double)DD * (double)HH * (double)WW);
        out[0] = (float)(j1 * invBN + 0.0008 * ws[24] * invBN);
    }
}

extern "C" void kernel_launch(void* const* d_in, const int* in_sizes, int n_in,
                              void* d_out, int out_size, void* d_ws, size_t ws_size,
                              hipStream_t stream) {
    const float* yp  = (const float*)d_in[0];   // y_pred [2,4,128,128,128]
    const float* img = (const float*)d_in[1];   // image  [2,1,128,128,128]
    float* out = (float*)d_out;
    double* ws = (double*)d_ws;

    hipMemsetAsync(d_ws, 0, 25 * sizeof(double), stream);

    dim3 grid(BB * NBD * NBH);   // 512 blocks, fully resident
    rfcm_main<<<grid, NT, 0, stream>>>(yp, img, ws);
    rfcm_fin<<<1, 64, 0, stream>>>(ws, out);
}

// Round 8
// 129.797 us; speedup vs baseline: 1.5836x; 1.0245x over previous
//
#include <hip/hip_runtime.h>

// RFCM loss, fused single pass + finalize. B=2, K=4, D=H=W=128. Scalar out.
//
// mean(J1) = (1/(B*N)) * sum_{b,k} [ A_bk - Sim_bk^2 / Sm_bk ]
//   Sm=sum mem, Sim=sum mem*img, A=sum mem*img^2, mem=y_pred^2
// mean(J2) = (1/(B*N)) * sum_n [ Sm*Sbk - Sm^2 - sum_k m*bk + sum_k m^2 ]
//   bk = box27(mem_k) incl center, zero pad.
//
// R8: concurrency attack. Session invariant: R3/R5/R7 all fetch at ~1 TB/s
// regardless of load mechanism; R4/R6 (high wave count from spills) hit
// 2.1-2.8 TB/s -> fetch rate scales with concurrent requesters, not
// structure. So: 4 blocks/CU x 4 waves (NT=256, HR=8, SD=4, 1024 blocks,
// 40 KB LDS = exactly 4 resident) = 16 waves/CU, 4 independent DMA streams
// per CU vs R7's 2. Keep: global_load_lds staging, shfl w-halo, XCD slab
// swizzle. NEVER __launch_bounds__ min-waves (R4/R6: forced VGPR=64 ->
// 240-330 MB scratch spills).

#define BB 2
#define KK 4
#define DD 128
#define HH 128
#define WW 128
#define PLANE (HH * WW)
#define SD 4
#define NBD (DD / SD)   // 32
#define HR 8            // rows owned per block
#define NBH (HH / HR)   // 16
#define NT 256          // 32 w-lanes x 8 rows
#define LROW 128
#define LPL (10 * LROW)        // 10 rows per (plane,cluster)
#define LBUF (KK * LPL)        // 5120 floats = 20 KB per buffer

typedef const void __attribute__((address_space(1))) gvoid_t;
typedef void __attribute__((address_space(3))) svoid_t;
#define GLD(gp, lp) __builtin_amdgcn_global_load_lds((gvoid_t*)(gp), (svoid_t*)(lp), 16, 0, 0)

__global__ __launch_bounds__(NT) void rfcm_main(
    const float* __restrict__ yp, const float* __restrict__ img,
    double* __restrict__ ws)
{
    __shared__ __align__(16) float sbuf[2 * LBUF];   // 40 KB double buffer

    const int tid = threadIdx.x;
    const int wl  = tid & 31;       // w-lane: owns cols c0..c0+3
    const int hr  = tid >> 5;       // 0..7: own row
    const int c0  = wl << 2;

    // XCD swizzle: 64 slabs (b,dsb) x 16 h-tiles; slab -> XCD slab%8 so a
    // slab's 16 h-tiles share one XCD's L2 (halo re-reads hit L2).
    const int bid  = blockIdx.x;
    const int xcd  = bid & 7;
    const int idx  = bid >> 3;       // 0..127
    const int sl   = idx >> 4;       // 0..7
    const int ht   = idx & 15;
    const int slab = sl * 8 + xcd;   // 0..63
    const int b    = slab >> 5;
    const int dsb  = slab & 31;

    const int h0 = ht * HR;
    const int d0 = dsb * SD;
    const int h  = h0 + hr;

    // ---- DMA staging: plane t -> buf sel. Wave wv = cluster wv. ----
    // 10 rows x 128 cols per cluster: 5 two-row 64-lane GLD dwordx4.
    // LDS dest = wave-uniform base + lane*16 (HW requirement). h-clamped
    // rows are masked by msc/psc at extract (mapping-preserving).
    const int wv = tid >> 6;            // 0..3 == cluster
    const int L  = tid & 63;
    const int rr = L >> 5;              // row within 2-row chunk
    const int cl = (L & 31) << 2;       // col (floats)

    auto dma_plane = [&](int t, int sel) {
        if ((unsigned)t >= (unsigned)DD) return;
        const float* pb = yp + (size_t)((b * KK + wv) * DD + t) * PLANE;
        #pragma unroll
        for (int c = 0; c < 5; c++) {
            const int r = (c << 1) + rr;          // lds row 0..9
            int g = h0 - 1 + r;                   // global row, clamped
            g = g < 0 ? 0 : (g > HH - 1 ? HH - 1 : g);
            const float* gp = pb + g * WW + cl;
            float* lp = &sbuf[sel * LBUF + wv * LPL + (c << 1) * LROW];
            GLD(gp, lp);
        }
    };

    const bool okL = (wl > 0), okR = (wl < 31);
    const float msc = (h > 0)      ? 1.f : 0.f;
    const float psc = (h < HH - 1) ? 1.f : 0.f;

    // extract hw9 3x3 box sum + center squares for cluster k from buf sel
    auto extract = [&](int sel, int k, float4& s9, float4& mm) {
        const float* p3 = &sbuf[sel * LBUF + k * LPL + hr * LROW + c0];
        const float4 a4 = *(const float4*)(p3);              // row h-1
        const float4 b4 = *(const float4*)(p3 + LROW);       // row h
        const float4 c4 = *(const float4*)(p3 + 2 * LROW);   // row h+1
        const float4 sb = make_float4(b4.x*b4.x, b4.y*b4.y, b4.z*b4.z, b4.w*b4.w);
        mm = sb;
        float4 v;
        v.x = fmaf(a4.x*a4.x, msc, fmaf(c4.x*c4.x, psc, sb.x));
        v.y = fmaf(a4.y*a4.y, msc, fmaf(c4.y*c4.y, psc, sb.y));
        v.z = fmaf(a4.z*a4.z, msc, fmaf(c4.z*c4.z, psc, sb.z));
        v.w = fmaf(a4.w*a4.w, msc, fmaf(c4.w*c4.w, psc, sb.w));
        const float vL = okL ? __shfl_up(v.w, 1)   : 0.f;
        const float vR = okR ? __shfl_down(v.x, 1) : 0.f;
        s9.x = vL  + v.x + v.y;
        s9.y = v.x + v.y + v.z;
        s9.z = v.y + v.z + v.w;
        s9.w = v.z + v.w + vR;
    };

    // ---- prolog ----
    dma_plane(d0 - 1, 0);            // no-op when d0==0
    dma_plane(d0,     1);
    __syncthreads();                 // drains both

    float4 s9p[KK], s9c[KK], mc[KK], dum;
    const bool vprev = (d0 > 0);
    #pragma unroll
    for (int k = 0; k < KK; k++) {
        if (vprev) extract(0, k, s9p[k], dum);
        else       s9p[k] = make_float4(0.f, 0.f, 0.f, 0.f);
        extract(1, k, s9c[k], mc[k]);
    }
    __syncthreads();                 // buf0 reads done -> safe to re-DMA
    dma_plane(d0 + 1, 0);

    float smf[KK] = {0,0,0,0}, sif[KK] = {0,0,0,0}, saf[KK] = {0,0,0,0};
    float j2f = 0.f;

    const float* imgb = img + (size_t)b * DD * PLANE + h * WW + c0;

    #pragma unroll
    for (int i = 0; i < SD; i++) {
        const int d = d0 + i;
        __syncthreads();                           // drains DMA(d+1 -> buf[i&1])
        if (i < SD - 1) dma_plane(d + 2, (i + 1) & 1);

        const float4 iv = *(const float4*)(imgb + (size_t)d * PLANE);
        const bool vn = (d + 1 < DD);

        float4 summ  = make_float4(0.f, 0.f, 0.f, 0.f);
        float4 sumbk = make_float4(0.f, 0.f, 0.f, 0.f);
        float4 cross = make_float4(0.f, 0.f, 0.f, 0.f);
        const float4 iv2 = make_float4(iv.x*iv.x, iv.y*iv.y, iv.z*iv.z, iv.w*iv.w);

        #pragma unroll
        for (int k = 0; k < KK; k++) {
            float4 s9n, mn;
            if (vn) extract(i & 1, k, s9n, mn);
            else { s9n = make_float4(0.f,0.f,0.f,0.f); mn = s9n; }

            const float4 m = mc[k];
            float4 bk;
            bk.x = s9p[k].x + s9c[k].x + s9n.x;
            bk.y = s9p[k].y + s9c[k].y + s9n.y;
            bk.z = s9p[k].z + s9c[k].z + s9n.z;
            bk.w = s9p[k].w + s9c[k].w + s9n.w;

            summ.x += m.x; summ.y += m.y; summ.z += m.z; summ.w += m.w;
            sumbk.x += bk.x; sumbk.y += bk.y; sumbk.z += bk.z; sumbk.w += bk.w;
            cross.x = fmaf(m.x, bk.x - m.x, cross.x);
            cross.y = fmaf(m.y, bk.y - m.y, cross.y);
            cross.z = fmaf(m.z, bk.z - m.z, cross.z);
            cross.w = fmaf(m.w, bk.w - m.w, cross.w);

            smf[k] += (m.x + m.y) + (m.z + m.w);
            sif[k] = fmaf(m.x, iv.x,  fmaf(m.y, iv.y,  fmaf(m.z, iv.z,  fmaf(m.w, iv.w,  sif[k]))));
            saf[k] = fmaf(m.x, iv2.x, fmaf(m.y, iv2.y, fmaf(m.z, iv2.z, fmaf(m.w, iv2.w, saf[k]))));

            s9p[k] = s9c[k]; s9c[k] = s9n; mc[k] = mn;
        }

        j2f += (summ.x * (sumbk.x - summ.x) - cross.x)
             + (summ.y * (sumbk.y - summ.y) - cross.y)
             + (summ.z * (sumbk.z - summ.z) - cross.z)
             + (summ.w * (sumbk.w - summ.w) - cross.w);
    }

    // ---- block reduction of 13 scalars ----
    double q[13];
    #pragma unroll
    for (int k = 0; k < KK; k++) {
        q[k] = (double)smf[k]; q[4 + k] = (double)sif[k]; q[8 + k] = (double)saf[k];
    }
    q[12] = (double)j2f;

    #pragma unroll
    for (int qq = 0; qq < 13; qq++) {
        double v = q[qq];
        #pragma unroll
        for (int off = 32; off > 0; off >>= 1) v += __shfl_down(v, off, 64);
        q[qq] = v;
    }

    __syncthreads();                 // sbuf reads done; reuse as scratch
    double* red = (double*)sbuf;
    const int lane = tid & 63, wid = tid >> 6;
    if (lane == 0) {
        #pragma unroll
        for (int qq = 0; qq < 13; qq++) red[wid * 13 + qq] = q[qq];
    }
    __syncthreads();
    if (tid < 13) {
        const double sfin = red[tid] + red[13 + tid] + red[26 + tid] + red[39 + tid];
        int idxo;
        if      (tid < 4)  idxo = b * KK + tid;              // Sm
        else if (tid < 8)  idxo = 8  + b * KK + (tid - 4);   // Sim
        else if (tid < 12) idxo = 16 + b * KK + (tid - 8);   // A
        else               idxo = 24;                        // J2
        unsafeAtomicAdd(&ws[idxo], sfin);
    }
}

__global__ void rfcm_fin(const double* __restrict__ ws, float* __restrict__ out)
{
    if (threadIdx.x == 0 && blockIdx.x == 0) {
        double j1 = 0;
        #pragma unroll
        for (int i = 0; i < BB * KK; i++)
            j1 += ws[16 + i] - ws[8 + i] * ws[8 + i] / ws[i];
        const double invBN = 1.0 / ((double)BB * (double)DD * (double)HH * (double)WW);
        out[0] = (float)(j1 * invBN + 0.0008 * ws[24] * invBN);
    }
}

extern "C" void kernel_launch(void* const* d_in, const int* in_sizes, int n_in,
                              void* d_out, int out_size, void* d_ws, size_t ws_size,
                              hipStream_t stream) {
    const float* yp  = (const float*)d_in[0];   // y_pred [2,4,128,128,128]
    const float* img = (const float*)d_in[1];   // image  [2,1,128,128,128]
    float* out = (float*)d_out;
    double* ws = (double*)d_ws;

    hipMemsetAsync(d_ws, 0, 25 * sizeof(double), stream);

    dim3 grid(BB * NBD * NBH);   // 1024 blocks
    rfcm_main<<<grid, NT, 0, stream>>>(yp, img, ws);
    rfcm_fin<<<1, 64, 0, stream>>>(ws, out);
}